// Round 16
// baseline (217.940 us; speedup 1.0000x reference)
//
#include <hip/hip_runtime.h>

#define HEADS 4
#define CH 64
#define HC 256   // HEADS*CH
#define NEG 0.2f

typedef __attribute__((ext_vector_type(8))) short bf16x8;   // 8 bf16 (4 VGPRs)
typedef __attribute__((ext_vector_type(4))) float f32x4;    // MFMA accumulator

__device__ __forceinline__ unsigned short f2bf(float f){
  unsigned u = __float_as_uint(f);
  u += 0x7fffu + ((u >> 16) & 1u);          // round-to-nearest-even
  return (unsigned short)(u >> 16);
}
__device__ __forceinline__ float bf2f(unsigned short s){
  return __uint_as_float(((unsigned)s) << 16);
}

// ---------------- fast zero (runtime fillBuffer is slow for small buffers) ----------------
__global__ __launch_bounds__(256)
void zero_kernel(int4* __restrict__ p, int n4)
{
  int i = blockIdx.x*256 + threadIdx.x;
  if (i < n4) p[i] = make_int4(0,0,0,0);
}

// ---------------- CSR build (real edges only; self-loops analytic) ----------------
// XCD-range partition: range = blockIdx&7; each range-set streams all edges and
// filters dst into its 1/8 of node space -> writers of a dst-range share one
// XCD's L2 -> line writebacks merge.
__global__ __launch_bounds__(256)
void deg_count_kernel(const int* __restrict__ edst, int E, int N,
                      int* __restrict__ deg, int cpr)
{
  const int range = blockIdx.x & 7;
  const int lo = (int)(((long long)N * range) / 8);
  const int hi = (int)(((long long)N * (range+1)) / 8);
  const int stride = cpr * 256;
  for (int e = (blockIdx.x >> 3)*256 + threadIdx.x; e < E; e += stride){
    int d = edst[e];
    if (d >= lo && d < hi) atomicAdd(deg + d, 1);
  }
}

__global__ __launch_bounds__(256)
void scan1_kernel(const int* __restrict__ deg, int* __restrict__ excl,
                  int* __restrict__ bsum, int N)
{
  __shared__ int sm[256];
  int i = blockIdx.x*256 + threadIdx.x;
  int v = (i < N) ? deg[i] : 0;
  sm[threadIdx.x] = v; __syncthreads();
  for (int off = 1; off < 256; off <<= 1){
    int t = (threadIdx.x >= off) ? sm[threadIdx.x - off] : 0;
    __syncthreads();
    sm[threadIdx.x] += t;
    __syncthreads();
  }
  if (i < N) excl[i] = sm[threadIdx.x] - v;
  if (threadIdx.x == 255) bsum[blockIdx.x] = sm[255];
}

__global__ __launch_bounds__(512)
void scan2_kernel(int* __restrict__ bsum, int nb)
{
  __shared__ int sm[512];
  int v = (threadIdx.x < nb) ? bsum[threadIdx.x] : 0;
  sm[threadIdx.x] = v; __syncthreads();
  for (int off = 1; off < 512; off <<= 1){
    int t = (threadIdx.x >= off) ? sm[threadIdx.x - off] : 0;
    __syncthreads();
    sm[threadIdx.x] += t;
    __syncthreads();
  }
  if (threadIdx.x < nb) bsum[threadIdx.x] = sm[threadIdx.x] - v;
}

__global__ __launch_bounds__(256)
void scan3_kernel(int* __restrict__ excl, const int* __restrict__ bsum,
                  int* __restrict__ cursor, int N)
{
  int i = blockIdx.x*256 + threadIdx.x;
  if (i >= N) return;
  int r = excl[i] + bsum[blockIdx.x];
  excl[i] = r; cursor[i] = r;
}

__global__ __launch_bounds__(256)
void scatter_kernel(const int* __restrict__ esrc, const int* __restrict__ edst,
                    int E, int N, int* __restrict__ cursor, int* __restrict__ ssrc,
                    int cpr)
{
  const int range = blockIdx.x & 7;
  const int lo = (int)(((long long)N * range) / 8);
  const int hi = (int)(((long long)N * (range+1)) / 8);
  const int stride = cpr * 256;
  for (int e = (blockIdx.x >> 3)*256 + threadIdx.x; e < E; e += stride){
    int d = edst[e];
    if (d >= lo && d < hi){
      int pos = atomicAdd(cursor + d, 1);
      ssrc[pos] = esrc[e];
    }
  }
}

// ---------------- attention-weight folding (ONCE per layer; 1 block) ----------------
template<int FIN>
__global__ void fold_kernel(const float* __restrict__ W,
                            const float* __restrict__ att_src, const float* __restrict__ att_dst,
                            float* __restrict__ wfold)
{
  int o = threadIdx.x;               // o = f*8 + j
  int f = o >> 3, j = o & 7;
  int h = j & 3;
  const float* att = (j < 4) ? att_src : att_dst;
  float acc = 0.f;
#pragma unroll
  for (int c = 0; c < CH; ++c)
    acc += W[(size_t)f*HC + h*CH + c] * att[h*CH + c];
  wfold[f*8 + j] = acc;
}

// a_s[n,h], a_d[n,h] = x[n,:] @ wfold ; 8 threads per node, 32 nodes/block (fp32 x)
template<int FIN>
__global__ __launch_bounds__(256)
void att_kernel(const float* __restrict__ x, const float* __restrict__ wfold,
                float* __restrict__ a_s, float* __restrict__ a_d, int N)
{
  __shared__ float xs[32][FIN];
  __shared__ float wf[FIN*8];
  const int t = threadIdx.x;
  const int n0 = blockIdx.x * 32;
  for (int i = t; i < FIN*8; i += 256) wf[i] = wfold[i];
  for (int i = t; i < 32*FIN; i += 256){
    int n = n0 + i / FIN;
    xs[i/FIN][i%FIN] = (n < N) ? x[(size_t)n*FIN + (i % FIN)] : 0.f;
  }
  __syncthreads();
  const int nn = t >> 3, j = t & 7;
  const int n = n0 + nn;
  if (n >= N) return;
  float acc = 0.f;
#pragma unroll
  for (int f = 0; f < FIN; ++f) acc += xs[nn][f] * wf[f*8 + j];
  if (j < 4) a_s[(size_t)n*4 + j]     = acc;
  else       a_d[(size_t)n*4 + (j-4)] = acc;
}

// same but x is bf16 [n][64]
__global__ __launch_bounds__(256)
void att_bf_kernel(const unsigned short* __restrict__ xb, const float* __restrict__ wfold,
                   float* __restrict__ a_s, float* __restrict__ a_d, int N)
{
  __shared__ float xs[32][64];
  __shared__ float wf[64*8];
  const int t = threadIdx.x;
  const int n0 = blockIdx.x * 32;
  const ushort4* xb4 = (const ushort4*)xb;
  for (int i = t; i < 64*8; i += 256) wf[i] = wfold[i];
  for (int i4 = t; i4 < 32*16; i4 += 256){
    int n = n0 + (i4 >> 4);
    ushort4 v = (n < N) ? xb4[(size_t)n*16 + (i4 & 15)] : make_ushort4(0,0,0,0);
    float* dst = &xs[i4 >> 4][(i4 & 15)*4];
    dst[0] = bf2f(v.x); dst[1] = bf2f(v.y); dst[2] = bf2f(v.z); dst[3] = bf2f(v.w);
  }
  __syncthreads();
  const int nn = t >> 3, j = t & 7;
  const int n = n0 + nn;
  if (n >= N) return;
  float acc = 0.f;
#pragma unroll
  for (int f = 0; f < 64; ++f) acc += xs[nn][f] * wf[f*8 + j];
  if (j < 4) a_s[(size_t)n*4 + j]     = acc;
  else       a_d[(size_t)n*4 + (j-4)] = acc;
}

// ---------------- layer 1: group-per-dst z-aggregation + fp32 projection ----------------
// Inner loop 4-edge batched: 4 independent gathers in flight per group.
__global__ __launch_bounds__(256)
void gat_l1_kernel(const int* __restrict__ rowstart, const int* __restrict__ ssrc,
                   int N, int E,
                   const float* __restrict__ a_s, const float* __restrict__ a_d,
                   const float* __restrict__ x, const float* __restrict__ W1,
                   const float* __restrict__ b1,
                   unsigned short* __restrict__ featb)
{
  __shared__ int    slds[4][4][16];
  __shared__ float4 wlds[4][4][16];
  __shared__ float4 zlds[16][8];     // [row][f] = (z_h0, z_h1, z_h2, z_h3)
  __shared__ float4 dnlds[16];
  const int t    = threadIdx.x;
  const int wv   = t >> 6;
  const int lane = t & 63;
  const int grp  = lane >> 4;
  const int fq   = lane & 15;
  const int p    = fq >> 3;          // parity
  const int f    = fq & 7;           // feature
  const int r    = wv*4 + grp;       // local row 0..15
  const int d    = blockIdx.x*16 + r;

  float z0=0.f, z1=0.f, z2=0.f, z3=0.f;
  float dn0=0.f, dn1=0.f, dn2=0.f, dn3=0.f;
  if (d < N){
    const int start = rowstart[d];
    const int end   = (d == N-1) ? E : rowstart[d+1];
    const float4 ad4 = *(const float4*)(a_d + (size_t)d*4);
    // self-loop (not stored in CSR): parity 0 adds it exactly once
    {
      const float4 asd = *(const float4*)(a_s + (size_t)d*4);
      float v, es0, es1, es2, es3;
      v = asd.x + ad4.x; v = v > 0.f ? v : NEG*v; es0 = __expf(v);
      v = asd.y + ad4.y; v = v > 0.f ? v : NEG*v; es1 = __expf(v);
      v = asd.z + ad4.z; v = v > 0.f ? v : NEG*v; es2 = __expf(v);
      v = asd.w + ad4.w; v = v > 0.f ? v : NEG*v; es3 = __expf(v);
      if (p == 0){
        const float xv = x[(size_t)d*8 + f];
        z0 += es0*xv; z1 += es1*xv; z2 += es2*xv; z3 += es3*xv;
        dn0 += es0; dn1 += es1; dn2 += es2; dn3 += es3;
      }
    }
    for (int base = start; base < end; base += 16){
      const int cnt = min(16, end - base);
      int sreg = 0; float e0=0.f, e1=0.f, e2=0.f, e3=0.f;
      if (fq < cnt){
        sreg = ssrc[base + fq];
        const float4 as4 = *(const float4*)(a_s + (size_t)sreg*4);
        float v;
        v = as4.x + ad4.x; v = v > 0.f ? v : NEG*v; e0 = __expf(v);
        v = as4.y + ad4.y; v = v > 0.f ? v : NEG*v; e1 = __expf(v);
        v = as4.z + ad4.z; v = v > 0.f ? v : NEG*v; e2 = __expf(v);
        v = as4.w + ad4.w; v = v > 0.f ? v : NEG*v; e3 = __expf(v);
      }
      slds[wv][grp][fq] = sreg;
      wlds[wv][grp][fq] = make_float4(e0, e1, e2, e3);
      __builtin_amdgcn_wave_barrier();
      int k = p;
      // 4-edge batch (this parity): gathers issued together, FMAs in k-order
      for (; k + 6 < cnt; k += 8){
        const int sA = slds[wv][grp][k],   sB = slds[wv][grp][k+2];
        const int sC = slds[wv][grp][k+4], sD = slds[wv][grp][k+6];
        const float xA = x[(size_t)sA*8 + f];
        const float xB = x[(size_t)sB*8 + f];
        const float xC = x[(size_t)sC*8 + f];
        const float xD = x[(size_t)sD*8 + f];
        const float4 wA = wlds[wv][grp][k],   wB = wlds[wv][grp][k+2];
        const float4 wC = wlds[wv][grp][k+4], wD = wlds[wv][grp][k+6];
        z0 += wA.x*xA; z1 += wA.y*xA; z2 += wA.z*xA; z3 += wA.w*xA;
        dn0 += wA.x; dn1 += wA.y; dn2 += wA.z; dn3 += wA.w;
        z0 += wB.x*xB; z1 += wB.y*xB; z2 += wB.z*xB; z3 += wB.w*xB;
        dn0 += wB.x; dn1 += wB.y; dn2 += wB.z; dn3 += wB.w;
        z0 += wC.x*xC; z1 += wC.y*xC; z2 += wC.z*xC; z3 += wC.w*xC;
        dn0 += wC.x; dn1 += wC.y; dn2 += wC.z; dn3 += wC.w;
        z0 += wD.x*xD; z1 += wD.y*xD; z2 += wD.z*xD; z3 += wD.w*xD;
        dn0 += wD.x; dn1 += wD.y; dn2 += wD.z; dn3 += wD.w;
      }
      for (; k < cnt; k += 2){
        const int    s  = slds[wv][grp][k];
        const float4 w4 = wlds[wv][grp][k];
        const float  xv = x[(size_t)s*8 + f];
        z0 += w4.x*xv; z1 += w4.y*xv; z2 += w4.z*xv; z3 += w4.w*xv;
        dn0 += w4.x; dn1 += w4.y; dn2 += w4.z; dn3 += w4.w;
      }
      __builtin_amdgcn_wave_barrier();
    }
  }
  // combine parities (lane ^ 8 stays within the 16-lane group)
  z0  += __shfl_xor(z0, 8);  z1  += __shfl_xor(z1, 8);
  z2  += __shfl_xor(z2, 8);  z3  += __shfl_xor(z3, 8);
  dn0 += __shfl_xor(dn0, 8); dn1 += __shfl_xor(dn1, 8);
  dn2 += __shfl_xor(dn2, 8); dn3 += __shfl_xor(dn3, 8);
  if (d >= N){ dn0=dn1=dn2=dn3=1.f; }
  if (fq < 8)  zlds[r][f] = make_float4(z0, z1, z2, z3);
  if (fq == 0) dnlds[r]   = make_float4(dn0, dn1, dn2, dn3);
  __syncthreads();
  // fp32 finish: wave wv handles rows wv*4..wv*4+3; lane = output channel
  float Wf[4][8];
#pragma unroll
  for (int h = 0; h < 4; ++h)
#pragma unroll
    for (int ff = 0; ff < 8; ++ff)
      Wf[h][ff] = W1[ff*HC + h*CH + lane];
  const float bc = b1[lane];
#pragma unroll
  for (int i = 0; i < 4; ++i){
    const int r2 = wv*4 + i;
    const int d2 = blockIdx.x*16 + r2;
    if (d2 >= N) break;
    const float4 dn = dnlds[r2];
    float a0=0.f, a1=0.f, a2=0.f, a3=0.f;
#pragma unroll
    for (int ff = 0; ff < 8; ++ff){
      const float4 q = zlds[r2][ff];
      a0 += q.x*Wf[0][ff]; a1 += q.y*Wf[1][ff];
      a2 += q.z*Wf[2][ff]; a3 += q.w*Wf[3][ff];
    }
    float val = 0.25f*(a0*__builtin_amdgcn_rcpf(dn.x) + a1*__builtin_amdgcn_rcpf(dn.y)
                     + a2*__builtin_amdgcn_rcpf(dn.z) + a3*__builtin_amdgcn_rcpf(dn.w));
    val = fmaxf(val + bc, 0.f);
    featb[(size_t)d2*CH + lane] = f2bf(val);
  }
}

// ---------------- W2 -> bf16 B-fragments ----------------
__global__ __launch_bounds__(256)
void w2fold_kernel(const float* __restrict__ W2, unsigned short* __restrict__ w2bf)
{
  int i = blockIdx.x*256 + threadIdx.x;      // 0..16383
  int j  = i & 7;
  int l  = (i >> 3) & 63;
  int nf = (i >> 9) & 3;
  int kc = i >> 11;
  int q = kc*32 + (l >> 4)*8 + j;
  int c = nf*16 + (l & 15);
  int f = q & 63, h = q >> 6;
  w2bf[i] = f2bf(W2[(size_t)f*HC + h*64 + c]);
}

// ---------------- layer 2: group-per-dst aggregation + fused MFMA finish ----------------
// Inner loop 4-edge batched: 4 independent 128B gathers in flight per group.
__global__ __launch_bounds__(256)
void gat_z_mfma_kernel(const int* __restrict__ rowstart, const int* __restrict__ ssrc,
                       int N, int E,
                       const float* __restrict__ a_s, const float* __restrict__ a_d,
                       const unsigned short* __restrict__ featb,
                       const unsigned short* __restrict__ w2bf,
                       const float* __restrict__ b2,
                       float* __restrict__ feat2)
{
  __shared__ int    slds[4][4][16];
  __shared__ float4 wlds[4][4][16];
  __shared__ unsigned short zlds[16][264];   // row stride 528B -> 2-way banks
  const int t    = threadIdx.x;
  const int wv   = t >> 6;
  const int lane = t & 63;
  const int grp  = lane >> 4;
  const int fq   = lane & 15;
  const int r    = wv*4 + grp;               // local row 0..15
  const int d    = blockIdx.x*16 + r;

  float z00=0,z01=0,z02=0,z03=0, z10=0,z11=0,z12=0,z13=0;
  float z20=0,z21=0,z22=0,z23=0, z30=0,z31=0,z32=0,z33=0;
  float dn0=1.f, dn1=1.f, dn2=1.f, dn3=1.f;  // safe default for d>=N
  if (d < N){
    const int start = rowstart[d];
    const int end   = (d == N-1) ? E : rowstart[d+1];
    const float4 ad4 = *(const float4*)(a_d + (size_t)d*4);
    const ushort4* __restrict__ fb4 = (const ushort4*)featb;
    // self-loop (den replicated per lane; z at own feature-quad)
    {
      const float4 asd = *(const float4*)(a_s + (size_t)d*4);
      float v, es0, es1, es2, es3;
      v = asd.x + ad4.x; v = v > 0.f ? v : NEG*v; es0 = __expf(v);
      v = asd.y + ad4.y; v = v > 0.f ? v : NEG*v; es1 = __expf(v);
      v = asd.z + ad4.z; v = v > 0.f ? v : NEG*v; es2 = __expf(v);
      v = asd.w + ad4.w; v = v > 0.f ? v : NEG*v; es3 = __expf(v);
      const ushort4 hv = fb4[(size_t)d*16 + fq];
      const float f0 = bf2f(hv.x), f1 = bf2f(hv.y), f2 = bf2f(hv.z), f3 = bf2f(hv.w);
      z00 = es0*f0; z01 = es0*f1; z02 = es0*f2; z03 = es0*f3;
      z10 = es1*f0; z11 = es1*f1; z12 = es1*f2; z13 = es1*f3;
      z20 = es2*f0; z21 = es2*f1; z22 = es2*f2; z23 = es2*f3;
      z30 = es3*f0; z31 = es3*f1; z32 = es3*f2; z33 = es3*f3;
      dn0 = es0; dn1 = es1; dn2 = es2; dn3 = es3;
    }
    for (int base = start; base < end; base += 16){
      const int cnt = min(16, end - base);
      int sreg = 0; float e0=0.f, e1=0.f, e2=0.f, e3=0.f;
      if (fq < cnt){
        sreg = ssrc[base + fq];
        const float4 as4 = *(const float4*)(a_s + (size_t)sreg*4);
        float v;
        v = as4.x + ad4.x; v = v > 0.f ? v : NEG*v; e0 = __expf(v);
        v = as4.y + ad4.y; v = v > 0.f ? v : NEG*v; e1 = __expf(v);
        v = as4.z + ad4.z; v = v > 0.f ? v : NEG*v; e2 = __expf(v);
        v = as4.w + ad4.w; v = v > 0.f ? v : NEG*v; e3 = __expf(v);
      }
      slds[wv][grp][fq] = sreg;
      wlds[wv][grp][fq] = make_float4(e0, e1, e2, e3);
      __builtin_amdgcn_wave_barrier();
#define ACC_EDGE(W4, HV) do{ \
        const float f0_ = bf2f((HV).x), f1_ = bf2f((HV).y), f2_ = bf2f((HV).z), f3_ = bf2f((HV).w); \
        z00 += (W4).x*f0_; z01 += (W4).x*f1_; z02 += (W4).x*f2_; z03 += (W4).x*f3_; \
        z10 += (W4).y*f0_; z11 += (W4).y*f1_; z12 += (W4).y*f2_; z13 += (W4).y*f3_; \
        z20 += (W4).z*f0_; z21 += (W4).z*f1_; z22 += (W4).z*f2_; z23 += (W4).z*f3_; \
        z30 += (W4).w*f0_; z31 += (W4).w*f1_; z32 += (W4).w*f2_; z33 += (W4).w*f3_; \
        dn0 += (W4).x; dn1 += (W4).y; dn2 += (W4).z; dn3 += (W4).w; }while(0)
      int k = 0;
      for (; k + 3 < cnt; k += 4){
        const int sA = slds[wv][grp][k],   sB = slds[wv][grp][k+1];
        const int sC = slds[wv][grp][k+2], sD = slds[wv][grp][k+3];
        const ushort4 hA = fb4[(size_t)sA*16 + fq];
        const ushort4 hB = fb4[(size_t)sB*16 + fq];
        const ushort4 hC = fb4[(size_t)sC*16 + fq];
        const ushort4 hD = fb4[(size_t)sD*16 + fq];
        const float4 wA = wlds[wv][grp][k],   wB = wlds[wv][grp][k+1];
        const float4 wC = wlds[wv][grp][k+2], wD = wlds[wv][grp][k+3];
        ACC_EDGE(wA, hA); ACC_EDGE(wB, hB); ACC_EDGE(wC, hC); ACC_EDGE(wD, hD);
      }
      for (; k < cnt; ++k){
        const int    s  = slds[wv][grp][k];
        const float4 w4 = wlds[wv][grp][k];
        const ushort4 hv = fb4[(size_t)s*16 + fq];
        ACC_EDGE(w4, hv);
      }
#undef ACC_EDGE
      __builtin_amdgcn_wave_barrier();
    }
  }
  {
    const float s0 = 0.25f*__builtin_amdgcn_rcpf(dn0);
    const float s1 = 0.25f*__builtin_amdgcn_rcpf(dn1);
    const float s2 = 0.25f*__builtin_amdgcn_rcpf(dn2);
    const float s3 = 0.25f*__builtin_amdgcn_rcpf(dn3);
    ushort4* zrow = (ushort4*)zlds[r];
    ushort4 o;
    o.x=f2bf(z00*s0); o.y=f2bf(z01*s0); o.z=f2bf(z02*s0); o.w=f2bf(z03*s0);
    zrow[ 0 + fq] = o;
    o.x=f2bf(z10*s1); o.y=f2bf(z11*s1); o.z=f2bf(z12*s1); o.w=f2bf(z13*s1);
    zrow[16 + fq] = o;
    o.x=f2bf(z20*s2); o.y=f2bf(z21*s2); o.z=f2bf(z22*s2); o.w=f2bf(z23*s2);
    zrow[32 + fq] = o;
    o.x=f2bf(z30*s3); o.y=f2bf(z31*s3); o.z=f2bf(z32*s3); o.w=f2bf(z33*s3);
    zrow[48 + fq] = o;
  }
  __syncthreads();
  const bf16x8* __restrict__ bfr = (const bf16x8*)w2bf;
  const int arow = lane & 15;
  const int kg   = lane >> 4;
  f32x4 acc = {0.f, 0.f, 0.f, 0.f};
#pragma unroll
  for (int kc = 0; kc < 8; ++kc){
    const bf16x8 a = *(const bf16x8*)(&zlds[arow][kc*32 + kg*8]);
    const bf16x8 b = bfr[(kc*4 + wv)*64 + lane];
    acc = __builtin_amdgcn_mfma_f32_16x16x32_bf16(a, b, acc, 0, 0, 0);
  }
  const int col = lane & 15;                 // C: col=lane&15, row=(lane>>4)*4+reg
  const float bias = b2[wv*16 + col];
#pragma unroll
  for (int reg = 0; reg < 4; ++reg){
    const int rr = blockIdx.x*16 + kg*4 + reg;
    if (rr < N)
      feat2[(size_t)rr*CH + wv*16 + col] = fmaxf(acc[reg] + bias, 0.f);
  }
}

// ---------------- pool + MLP ----------------
__global__ __launch_bounds__(256)
void pool_mlp_kernel(const float* __restrict__ feat,
                     const int* __restrict__ batch, int N,
                     const float* __restrict__ Wp1, const float* __restrict__ bp1,
                     const float* __restrict__ Wp2, const float* __restrict__ bp2,
                     float* __restrict__ out)
{
  const int g = blockIdx.x;
  __shared__ int seg[2];
  __shared__ float part[256];
  __shared__ float pooled[CH];
  if (threadIdx.x < 2){
    int target = g + (int)threadIdx.x;
    int lo = 0, hi = N;
    while (lo < hi){ int mid = (lo + hi) >> 1; if (batch[mid] < target) lo = mid + 1; else hi = mid; }
    seg[threadIdx.x] = lo;
  }
  __syncthreads();
  const int start = seg[0], end = seg[1];
  const int c = threadIdx.x & 63, w = threadIdx.x >> 6;
  float acc = 0.f;
  for (int n = start + w; n < end; n += 4)
    acc += feat[(size_t)n*CH + c];
  part[threadIdx.x] = acc;
  __syncthreads();
  if (threadIdx.x < CH){
    float s = part[threadIdx.x] + part[threadIdx.x+64] + part[threadIdx.x+128] + part[threadIdx.x+192];
    pooled[threadIdx.x] = s / fmaxf((float)(end - start), 1.f);
  }
  __syncthreads();
  float hid = 0.f;
  if (threadIdx.x < 32){
    float a2 = bp1[threadIdx.x];
#pragma unroll
    for (int k = 0; k < CH; ++k) a2 += pooled[k] * Wp1[k*32 + threadIdx.x];
    hid = fmaxf(a2, 0.f) * Wp2[threadIdx.x];
  }
#pragma unroll
  for (int off = 16; off; off >>= 1) hid += __shfl_down(hid, off);
  if (threadIdx.x == 0) out[g] = hid + bp2[0];
}

extern "C" void kernel_launch(void* const* d_in, const int* in_sizes, int n_in,
                              void* d_out, int out_size, void* d_ws, size_t ws_size,
                              hipStream_t stream)
{
  const float* x   = (const float*)d_in[0];
  const int*   ei  = (const int*)d_in[1];
  const int*   bat = (const int*)d_in[2];
  const float* W1  = (const float*)d_in[4];
  const float* as1 = (const float*)d_in[5];
  const float* ad1 = (const float*)d_in[6];
  const float* b1  = (const float*)d_in[7];
  const float* W2  = (const float*)d_in[8];
  const float* as2 = (const float*)d_in[9];
  const float* ad2 = (const float*)d_in[10];
  const float* b2  = (const float*)d_in[11];
  const float* Wp1 = (const float*)d_in[12];
  const float* bp1 = (const float*)d_in[13];
  const float* Wp2 = (const float*)d_in[14];
  const float* bp2 = (const float*)d_in[15];

  const int N = in_sizes[0] / 8;     // x is [N, 8]
  const int E = in_sizes[1] / 2;     // edge_index is [2, E]
  const int G = out_size;            // output is [G, 1]
  const int* esrc = ei;
  const int* edst = ei + E;

  char* wsb = (char*)d_ws;
  size_t o = 0;
  auto carve = [&](size_t bytes)->char*{
    char* p = wsb + o; o += (bytes + 255) & ~(size_t)255; return p;
  };
  unsigned short* featb = (unsigned short*)carve((size_t)N*CH*sizeof(unsigned short));
  unsigned short* w2bf  = (unsigned short*)carve((size_t)HC*CH*sizeof(unsigned short));
  float* a_s      = (float*)carve((size_t)N*HEADS*sizeof(float));
  float* a_d      = (float*)carve((size_t)N*HEADS*sizeof(float));
  float* feat2    = (float*)carve((size_t)N*CH*sizeof(float));
  float* wfold    = (float*)carve((size_t)64*8*sizeof(float));
  int*   rowstart = (int*)carve((size_t)N*sizeof(int));
  int*   cursor   = (int*)carve((size_t)N*sizeof(int));
  int*   deg      = (int*)carve((size_t)(N+4)*sizeof(int));   // +pad for int4 zero
  int*   bsum     = (int*)carve((size_t)512*sizeof(int));
  int*   ssrc     = (int*)carve((size_t)E*sizeof(int));

  const int nb1 = (N + 255) / 256;
  const int atb = (N + 31) / 32;
  const int gb  = (N + 15) / 16;     // group-per-dst kernels: 16 dst/block
  const int cpr = 512;               // chunks per XCD-range (grid-stride)
  const int csb = 8 * cpr;           // CSR-build grid
  const int n4  = (N + 3) / 4;       // int4 count for deg zero
  const int zb  = (n4 + 255) / 256;

  // ---- CSR build (real edges only; once, shared by both layers) ----
  zero_kernel<<<zb, 256, 0, stream>>>((int4*)deg, n4);
  deg_count_kernel<<<csb, 256, 0, stream>>>(edst, E, N, deg, cpr);
  scan1_kernel<<<nb1, 256, 0, stream>>>(deg, rowstart, bsum, N);
  scan2_kernel<<<1, 512, 0, stream>>>(bsum, nb1);
  scan3_kernel<<<nb1, 256, 0, stream>>>(rowstart, bsum, cursor, N);
  scatter_kernel<<<csb, 256, 0, stream>>>(esrc, edst, E, N, cursor, ssrc, cpr);

  // ---- layer 1 (Fin = 8): group-per-dst commuted aggregation, fp32 finish ----
  fold_kernel<8><<<1, 8*8, 0, stream>>>(W1, as1, ad1, wfold);
  att_kernel<8><<<atb, 256, 0, stream>>>(x, wfold, a_s, a_d, N);
  gat_l1_kernel<<<gb, 256, 0, stream>>>(rowstart, ssrc, N, E, a_s, a_d, x, W1, b1, featb);

  // ---- layer 2 (Fin = 64): group-per-dst aggregation + fused MFMA ----
  fold_kernel<64><<<1, 64*8, 0, stream>>>(W2, as2, ad2, wfold);
  att_bf_kernel<<<atb, 256, 0, stream>>>(featb, wfold, a_s, a_d, N);
  w2fold_kernel<<<64, 256, 0, stream>>>(W2, w2bf);
  gat_z_mfma_kernel<<<gb, 256, 0, stream>>>(rowstart, ssrc, N, E, a_s, a_d,
                                            featb, w2bf, b2, feat2);

  // ---- pool + MLP ----
  pool_mlp_kernel<<<G, 256, 0, stream>>>(feat2, bat, N, Wp1, bp1, Wp2, bp2, (float*)d_out);
}

// Round 17
// 200.452 us; speedup vs baseline: 1.0872x; 1.0872x over previous
//
#include <hip/hip_runtime.h>

#define HEADS 4
#define CH 64
#define HC 256   // HEADS*CH
#define NEG 0.2f

typedef __attribute__((ext_vector_type(8))) short bf16x8;   // 8 bf16 (4 VGPRs)
typedef __attribute__((ext_vector_type(4))) float f32x4;    // MFMA accumulator

__device__ __forceinline__ unsigned short f2bf(float f){
  unsigned u = __float_as_uint(f);
  u += 0x7fffu + ((u >> 16) & 1u);          // round-to-nearest-even
  return (unsigned short)(u >> 16);
}
__device__ __forceinline__ float bf2f(unsigned short s){
  return __uint_as_float(((unsigned)s) << 16);
}

// ---------------- fused prep: deg zero + fold8 + fold64 + w2fold (1 launch) ----------------
__global__ __launch_bounds__(256)
void prep_kernel(const float* __restrict__ W1, const float* __restrict__ as1, const float* __restrict__ ad1,
                 const float* __restrict__ W2, const float* __restrict__ as2, const float* __restrict__ ad2,
                 float* __restrict__ wfold1, float* __restrict__ wfold2,
                 unsigned short* __restrict__ w2bf,
                 int4* __restrict__ deg4, int n4)
{
  const int b = blockIdx.x;
  if (b == 0){
    int o = threadIdx.x;               // fold8: 64 outputs
    if (o < 64){
      int f = o >> 3, j = o & 7, h = j & 3;
      const float* att = (j < 4) ? as1 : ad1;
      float acc = 0.f;
#pragma unroll
      for (int c = 0; c < CH; ++c) acc += W1[(size_t)f*HC + h*CH + c] * att[h*CH + c];
      wfold1[o] = acc;
    }
  } else if (b <= 2){
    int o = (b-1)*256 + threadIdx.x;   // fold64: 512 outputs
    int f = o >> 3, j = o & 7, h = j & 3;
    const float* att = (j < 4) ? as2 : ad2;
    float acc = 0.f;
#pragma unroll
    for (int c = 0; c < CH; ++c) acc += W2[(size_t)f*HC + h*CH + c] * att[h*CH + c];
    wfold2[o] = acc;
  } else if (b < 67){
    int i = (b-3)*256 + threadIdx.x;   // w2fold: 16384 outputs
    int j  = i & 7;
    int l  = (i >> 3) & 63;
    int nf = (i >> 9) & 3;
    int kc = i >> 11;
    int q = kc*32 + (l >> 4)*8 + j;
    int c = nf*16 + (l & 15);
    int f = q & 63, h = q >> 6;
    w2bf[i] = f2bf(W2[(size_t)f*HC + h*64 + c]);
  } else {
    int i = (b-67)*256 + threadIdx.x;  // deg zero
    if (i < n4) deg4[i] = make_int4(0,0,0,0);
  }
}

// ---------------- CSR build (real edges only; self-loops analytic) ----------------
// XCD-range partition: range = blockIdx&7; each range-set streams all edges and
// filters dst into its 1/8 of node space -> writers of a dst-range share one
// XCD's L2 -> line writebacks merge.
__global__ __launch_bounds__(256)
void deg_count_kernel(const int* __restrict__ edst, int E, int N,
                      int* __restrict__ deg, int cpr)
{
  const int range = blockIdx.x & 7;
  const int lo = (int)(((long long)N * range) / 8);
  const int hi = (int)(((long long)N * (range+1)) / 8);
  const int stride = cpr * 256;
  for (int e = (blockIdx.x >> 3)*256 + threadIdx.x; e < E; e += stride){
    int d = edst[e];
    if (d >= lo && d < hi) atomicAdd(deg + d, 1);
  }
}

__global__ __launch_bounds__(256)
void scan1_kernel(const int* __restrict__ deg, int* __restrict__ excl,
                  int* __restrict__ bsum, int N)
{
  __shared__ int sm[256];
  int i = blockIdx.x*256 + threadIdx.x;
  int v = (i < N) ? deg[i] : 0;
  sm[threadIdx.x] = v; __syncthreads();
  for (int off = 1; off < 256; off <<= 1){
    int t = (threadIdx.x >= off) ? sm[threadIdx.x - off] : 0;
    __syncthreads();
    sm[threadIdx.x] += t;
    __syncthreads();
  }
  if (i < N) excl[i] = sm[threadIdx.x] - v;
  if (threadIdx.x == 255) bsum[blockIdx.x] = sm[255];
}

__global__ __launch_bounds__(512)
void scan2_kernel(int* __restrict__ bsum, int nb)
{
  __shared__ int sm[512];
  int v = (threadIdx.x < nb) ? bsum[threadIdx.x] : 0;
  sm[threadIdx.x] = v; __syncthreads();
  for (int off = 1; off < 512; off <<= 1){
    int t = (threadIdx.x >= off) ? sm[threadIdx.x - off] : 0;
    __syncthreads();
    sm[threadIdx.x] += t;
    __syncthreads();
  }
  if (threadIdx.x < nb) bsum[threadIdx.x] = sm[threadIdx.x] - v;
}

__global__ __launch_bounds__(256)
void scan3_kernel(int* __restrict__ excl, const int* __restrict__ bsum,
                  int* __restrict__ cursor, int N)
{
  int i = blockIdx.x*256 + threadIdx.x;
  if (i >= N) return;
  int r = excl[i] + bsum[blockIdx.x];
  excl[i] = r; cursor[i] = r;
}

__global__ __launch_bounds__(256)
void scatter_kernel(const int* __restrict__ esrc, const int* __restrict__ edst,
                    int E, int N, int* __restrict__ cursor, int* __restrict__ ssrc,
                    int cpr)
{
  const int range = blockIdx.x & 7;
  const int lo = (int)(((long long)N * range) / 8);
  const int hi = (int)(((long long)N * (range+1)) / 8);
  const int stride = cpr * 256;
  for (int e = (blockIdx.x >> 3)*256 + threadIdx.x; e < E; e += stride){
    int d = edst[e];
    if (d >= lo && d < hi){
      int pos = atomicAdd(cursor + d, 1);
      ssrc[pos] = esrc[e];
    }
  }
}

// ---------------- layer-1 attention logits ----------------
// a_s[n,h], a_d[n,h] = x[n,:] @ wfold ; 8 threads per node, 32 nodes/block (fp32 x)
template<int FIN>
__global__ __launch_bounds__(256)
void att_kernel(const float* __restrict__ x, const float* __restrict__ wfold,
                float* __restrict__ a_s, float* __restrict__ a_d, int N)
{
  __shared__ float xs[32][FIN];
  __shared__ float wf[FIN*8];
  const int t = threadIdx.x;
  const int n0 = blockIdx.x * 32;
  for (int i = t; i < FIN*8; i += 256) wf[i] = wfold[i];
  for (int i = t; i < 32*FIN; i += 256){
    int n = n0 + i / FIN;
    xs[i/FIN][i%FIN] = (n < N) ? x[(size_t)n*FIN + (i % FIN)] : 0.f;
  }
  __syncthreads();
  const int nn = t >> 3, j = t & 7;
  const int n = n0 + nn;
  if (n >= N) return;
  float acc = 0.f;
#pragma unroll
  for (int f = 0; f < FIN; ++f) acc += xs[nn][f] * wf[f*8 + j];
  if (j < 4) a_s[(size_t)n*4 + j]     = acc;
  else       a_d[(size_t)n*4 + (j-4)] = acc;
}

// ---------------- layer 1: group-per-dst z-aggregation + fp32 projection ----------------
// Epilogue FUSES layer-2 attention logits (fp32 rows staged to LDS, a_s2/a_d2 out).
__global__ __launch_bounds__(256)
void gat_l1_kernel(const int* __restrict__ rowstart, const int* __restrict__ ssrc,
                   int N, int E,
                   const float* __restrict__ a_s, const float* __restrict__ a_d,
                   const float* __restrict__ x, const float* __restrict__ W1,
                   const float* __restrict__ b1,
                   const float* __restrict__ wfold2,
                   unsigned short* __restrict__ featb,
                   float* __restrict__ a_s2, float* __restrict__ a_d2)
{
  __shared__ int    slds[4][4][16];
  __shared__ float4 wlds[4][4][16];
  __shared__ float4 zlds[16][8];     // [row][f] = (z_h0, z_h1, z_h2, z_h3)
  __shared__ float4 dnlds[16];
  __shared__ float  flds[16][65];    // fp32 feature rows (+1 pad: bank-spread)
  __shared__ float  wf2[512];        // wfold2 cache
  const int t    = threadIdx.x;
  const int wv   = t >> 6;
  const int lane = t & 63;
  const int grp  = lane >> 4;
  const int fq   = lane & 15;
  const int p    = fq >> 3;          // parity
  const int f    = fq & 7;           // feature
  const int r    = wv*4 + grp;       // local row 0..15
  const int d    = blockIdx.x*16 + r;

  wf2[t] = wfold2[t];                // 256 of 512
  wf2[256 + t] = wfold2[256 + t];

  float z0=0.f, z1=0.f, z2=0.f, z3=0.f;
  float dn0=0.f, dn1=0.f, dn2=0.f, dn3=0.f;
  if (d < N){
    const int start = rowstart[d];
    const int end   = (d == N-1) ? E : rowstart[d+1];
    const float4 ad4 = *(const float4*)(a_d + (size_t)d*4);
    // self-loop (not stored in CSR): parity 0 adds it exactly once
    {
      const float4 asd = *(const float4*)(a_s + (size_t)d*4);
      float v, es0, es1, es2, es3;
      v = asd.x + ad4.x; v = v > 0.f ? v : NEG*v; es0 = __expf(v);
      v = asd.y + ad4.y; v = v > 0.f ? v : NEG*v; es1 = __expf(v);
      v = asd.z + ad4.z; v = v > 0.f ? v : NEG*v; es2 = __expf(v);
      v = asd.w + ad4.w; v = v > 0.f ? v : NEG*v; es3 = __expf(v);
      if (p == 0){
        const float xv = x[(size_t)d*8 + f];
        z0 += es0*xv; z1 += es1*xv; z2 += es2*xv; z3 += es3*xv;
        dn0 += es0; dn1 += es1; dn2 += es2; dn3 += es3;
      }
    }
    for (int base = start; base < end; base += 16){
      const int cnt = min(16, end - base);
      int sreg = 0; float e0=0.f, e1=0.f, e2=0.f, e3=0.f;
      if (fq < cnt){
        sreg = ssrc[base + fq];
        const float4 as4 = *(const float4*)(a_s + (size_t)sreg*4);
        float v;
        v = as4.x + ad4.x; v = v > 0.f ? v : NEG*v; e0 = __expf(v);
        v = as4.y + ad4.y; v = v > 0.f ? v : NEG*v; e1 = __expf(v);
        v = as4.z + ad4.z; v = v > 0.f ? v : NEG*v; e2 = __expf(v);
        v = as4.w + ad4.w; v = v > 0.f ? v : NEG*v; e3 = __expf(v);
      }
      slds[wv][grp][fq] = sreg;
      wlds[wv][grp][fq] = make_float4(e0, e1, e2, e3);
      __builtin_amdgcn_wave_barrier();
      int k = p;
      for (; k + 6 < cnt; k += 8){
        const int sA = slds[wv][grp][k],   sB = slds[wv][grp][k+2];
        const int sC = slds[wv][grp][k+4], sD = slds[wv][grp][k+6];
        const float xA = x[(size_t)sA*8 + f];
        const float xB = x[(size_t)sB*8 + f];
        const float xC = x[(size_t)sC*8 + f];
        const float xD = x[(size_t)sD*8 + f];
        const float4 wA = wlds[wv][grp][k],   wB = wlds[wv][grp][k+2];
        const float4 wC = wlds[wv][grp][k+4], wD = wlds[wv][grp][k+6];
        z0 += wA.x*xA; z1 += wA.y*xA; z2 += wA.z*xA; z3 += wA.w*xA;
        dn0 += wA.x; dn1 += wA.y; dn2 += wA.z; dn3 += wA.w;
        z0 += wB.x*xB; z1 += wB.y*xB; z2 += wB.z*xB; z3 += wB.w*xB;
        dn0 += wB.x; dn1 += wB.y; dn2 += wB.z; dn3 += wB.w;
        z0 += wC.x*xC; z1 += wC.y*xC; z2 += wC.z*xC; z3 += wC.w*xC;
        dn0 += wC.x; dn1 += wC.y; dn2 += wC.z; dn3 += wC.w;
        z0 += wD.x*xD; z1 += wD.y*xD; z2 += wD.z*xD; z3 += wD.w*xD;
        dn0 += wD.x; dn1 += wD.y; dn2 += wD.z; dn3 += wD.w;
      }
      for (; k < cnt; k += 2){
        const int    s  = slds[wv][grp][k];
        const float4 w4 = wlds[wv][grp][k];
        const float  xv = x[(size_t)s*8 + f];
        z0 += w4.x*xv; z1 += w4.y*xv; z2 += w4.z*xv; z3 += w4.w*xv;
        dn0 += w4.x; dn1 += w4.y; dn2 += w4.z; dn3 += w4.w;
      }
      __builtin_amdgcn_wave_barrier();
    }
  }
  // combine parities (lane ^ 8 stays within the 16-lane group)
  z0  += __shfl_xor(z0, 8);  z1  += __shfl_xor(z1, 8);
  z2  += __shfl_xor(z2, 8);  z3  += __shfl_xor(z3, 8);
  dn0 += __shfl_xor(dn0, 8); dn1 += __shfl_xor(dn1, 8);
  dn2 += __shfl_xor(dn2, 8); dn3 += __shfl_xor(dn3, 8);
  if (d >= N){ dn0=dn1=dn2=dn3=1.f; }
  if (fq < 8)  zlds[r][f] = make_float4(z0, z1, z2, z3);
  if (fq == 0) dnlds[r]   = make_float4(dn0, dn1, dn2, dn3);
  __syncthreads();
  // fp32 finish: wave wv handles rows wv*4..wv*4+3; lane = output channel
  float Wf[4][8];
#pragma unroll
  for (int h = 0; h < 4; ++h)
#pragma unroll
    for (int ff = 0; ff < 8; ++ff)
      Wf[h][ff] = W1[ff*HC + h*CH + lane];
  const float bc = b1[lane];
#pragma unroll
  for (int i = 0; i < 4; ++i){
    const int r2 = wv*4 + i;
    const int d2 = blockIdx.x*16 + r2;
    if (d2 >= N) break;
    const float4 dn = dnlds[r2];
    float a0=0.f, a1=0.f, a2=0.f, a3=0.f;
#pragma unroll
    for (int ff = 0; ff < 8; ++ff){
      const float4 q = zlds[r2][ff];
      a0 += q.x*Wf[0][ff]; a1 += q.y*Wf[1][ff];
      a2 += q.z*Wf[2][ff]; a3 += q.w*Wf[3][ff];
    }
    float val = 0.25f*(a0*__builtin_amdgcn_rcpf(dn.x) + a1*__builtin_amdgcn_rcpf(dn.y)
                     + a2*__builtin_amdgcn_rcpf(dn.z) + a3*__builtin_amdgcn_rcpf(dn.w));
    val = fmaxf(val + bc, 0.f);
    featb[(size_t)d2*CH + lane] = f2bf(val);
    flds[r2][lane] = val;
  }
  __syncthreads();
  // fused layer-2 logits: a_s2/a_d2 = row @ wfold2 (separate buffers: no race
  // with layer-1 a_s/a_d still being gathered by other blocks)
  if (t < 128){
    const int nn = t >> 3, j = t & 7;
    const int n = blockIdx.x*16 + nn;
    if (n < N){
      float acc = 0.f;
#pragma unroll
      for (int ch = 0; ch < 64; ++ch) acc += flds[nn][ch] * wf2[ch*8 + j];
      if (j < 4) a_s2[(size_t)n*4 + j]     = acc;
      else       a_d2[(size_t)n*4 + (j-4)] = acc;
    }
  }
}

// ---------------- layer 2: group-per-dst aggregation + fused MFMA finish ----------------
__global__ __launch_bounds__(256)
void gat_z_mfma_kernel(const int* __restrict__ rowstart, const int* __restrict__ ssrc,
                       int N, int E,
                       const float* __restrict__ a_s, const float* __restrict__ a_d,
                       const unsigned short* __restrict__ featb,
                       const unsigned short* __restrict__ w2bf,
                       const float* __restrict__ b2,
                       float* __restrict__ feat2)
{
  __shared__ int    slds[4][4][16];
  __shared__ float4 wlds[4][4][16];
  __shared__ unsigned short zlds[16][264];   // row stride 528B -> 2-way banks
  const int t    = threadIdx.x;
  const int wv   = t >> 6;
  const int lane = t & 63;
  const int grp  = lane >> 4;
  const int fq   = lane & 15;
  const int r    = wv*4 + grp;               // local row 0..15
  const int d    = blockIdx.x*16 + r;

  float z00=0,z01=0,z02=0,z03=0, z10=0,z11=0,z12=0,z13=0;
  float z20=0,z21=0,z22=0,z23=0, z30=0,z31=0,z32=0,z33=0;
  float dn0=1.f, dn1=1.f, dn2=1.f, dn3=1.f;  // safe default for d>=N
  if (d < N){
    const int start = rowstart[d];
    const int end   = (d == N-1) ? E : rowstart[d+1];
    const float4 ad4 = *(const float4*)(a_d + (size_t)d*4);
    const ushort4* __restrict__ fb4 = (const ushort4*)featb;
    // self-loop (den replicated per lane; z at own feature-quad)
    {
      const float4 asd = *(const float4*)(a_s + (size_t)d*4);
      float v, es0, es1, es2, es3;
      v = asd.x + ad4.x; v = v > 0.f ? v : NEG*v; es0 = __expf(v);
      v = asd.y + ad4.y; v = v > 0.f ? v : NEG*v; es1 = __expf(v);
      v = asd.z + ad4.z; v = v > 0.f ? v : NEG*v; es2 = __expf(v);
      v = asd.w + ad4.w; v = v > 0.f ? v : NEG*v; es3 = __expf(v);
      const ushort4 hv = fb4[(size_t)d*16 + fq];
      const float f0 = bf2f(hv.x), f1 = bf2f(hv.y), f2 = bf2f(hv.z), f3 = bf2f(hv.w);
      z00 = es0*f0; z01 = es0*f1; z02 = es0*f2; z03 = es0*f3;
      z10 = es1*f0; z11 = es1*f1; z12 = es1*f2; z13 = es1*f3;
      z20 = es2*f0; z21 = es2*f1; z22 = es2*f2; z23 = es2*f3;
      z30 = es3*f0; z31 = es3*f1; z32 = es3*f2; z33 = es3*f3;
      dn0 = es0; dn1 = es1; dn2 = es2; dn3 = es3;
    }
    for (int base = start; base < end; base += 16){
      const int cnt = min(16, end - base);
      int sreg = 0; float e0=0.f, e1=0.f, e2=0.f, e3=0.f;
      if (fq < cnt){
        sreg = ssrc[base + fq];
        const float4 as4 = *(const float4*)(a_s + (size_t)sreg*4);
        float v;
        v = as4.x + ad4.x; v = v > 0.f ? v : NEG*v; e0 = __expf(v);
        v = as4.y + ad4.y; v = v > 0.f ? v : NEG*v; e1 = __expf(v);
        v = as4.z + ad4.z; v = v > 0.f ? v : NEG*v; e2 = __expf(v);
        v = as4.w + ad4.w; v = v > 0.f ? v : NEG*v; e3 = __expf(v);
      }
      slds[wv][grp][fq] = sreg;
      wlds[wv][grp][fq] = make_float4(e0, e1, e2, e3);
      __builtin_amdgcn_wave_barrier();
#define ACC_EDGE(W4, HV) do{ \
        const float f0_ = bf2f((HV).x), f1_ = bf2f((HV).y), f2_ = bf2f((HV).z), f3_ = bf2f((HV).w); \
        z00 += (W4).x*f0_; z01 += (W4).x*f1_; z02 += (W4).x*f2_; z03 += (W4).x*f3_; \
        z10 += (W4).y*f0_; z11 += (W4).y*f1_; z12 += (W4).y*f2_; z13 += (W4).y*f3_; \
        z20 += (W4).z*f0_; z21 += (W4).z*f1_; z22 += (W4).z*f2_; z23 += (W4).z*f3_; \
        z30 += (W4).w*f0_; z31 += (W4).w*f1_; z32 += (W4).w*f2_; z33 += (W4).w*f3_; \
        dn0 += (W4).x; dn1 += (W4).y; dn2 += (W4).z; dn3 += (W4).w; }while(0)
      int k = 0;
      for (; k + 3 < cnt; k += 4){
        const int sA = slds[wv][grp][k],   sB = slds[wv][grp][k+1];
        const int sC = slds[wv][grp][k+2], sD = slds[wv][grp][k+3];
        const ushort4 hA = fb4[(size_t)sA*16 + fq];
        const ushort4 hB = fb4[(size_t)sB*16 + fq];
        const ushort4 hC = fb4[(size_t)sC*16 + fq];
        const ushort4 hD = fb4[(size_t)sD*16 + fq];
        const float4 wA = wlds[wv][grp][k],   wB = wlds[wv][grp][k+1];
        const float4 wC = wlds[wv][grp][k+2], wD = wlds[wv][grp][k+3];
        ACC_EDGE(wA, hA); ACC_EDGE(wB, hB); ACC_EDGE(wC, hC); ACC_EDGE(wD, hD);
      }
      for (; k < cnt; ++k){
        const int    s  = slds[wv][grp][k];
        const float4 w4 = wlds[wv][grp][k];
        const ushort4 hv = fb4[(size_t)s*16 + fq];
        ACC_EDGE(w4, hv);
      }
#undef ACC_EDGE
      __builtin_amdgcn_wave_barrier();
    }
  }
  {
    const float s0 = 0.25f*__builtin_amdgcn_rcpf(dn0);
    const float s1 = 0.25f*__builtin_amdgcn_rcpf(dn1);
    const float s2 = 0.25f*__builtin_amdgcn_rcpf(dn2);
    const float s3 = 0.25f*__builtin_amdgcn_rcpf(dn3);
    ushort4* zrow = (ushort4*)zlds[r];
    ushort4 o;
    o.x=f2bf(z00*s0); o.y=f2bf(z01*s0); o.z=f2bf(z02*s0); o.w=f2bf(z03*s0);
    zrow[ 0 + fq] = o;
    o.x=f2bf(z10*s1); o.y=f2bf(z11*s1); o.z=f2bf(z12*s1); o.w=f2bf(z13*s1);
    zrow[16 + fq] = o;
    o.x=f2bf(z20*s2); o.y=f2bf(z21*s2); o.z=f2bf(z22*s2); o.w=f2bf(z23*s2);
    zrow[32 + fq] = o;
    o.x=f2bf(z30*s3); o.y=f2bf(z31*s3); o.z=f2bf(z32*s3); o.w=f2bf(z33*s3);
    zrow[48 + fq] = o;
  }
  __syncthreads();
  const bf16x8* __restrict__ bfr = (const bf16x8*)w2bf;
  const int arow = lane & 15;
  const int kg   = lane >> 4;
  f32x4 acc = {0.f, 0.f, 0.f, 0.f};
#pragma unroll
  for (int kc = 0; kc < 8; ++kc){
    const bf16x8 a = *(const bf16x8*)(&zlds[arow][kc*32 + kg*8]);
    const bf16x8 b = bfr[(kc*4 + wv)*64 + lane];
    acc = __builtin_amdgcn_mfma_f32_16x16x32_bf16(a, b, acc, 0, 0, 0);
  }
  const int col = lane & 15;                 // C: col=lane&15, row=(lane>>4)*4+reg
  const float bias = b2[wv*16 + col];
#pragma unroll
  for (int reg = 0; reg < 4; ++reg){
    const int rr = blockIdx.x*16 + kg*4 + reg;
    if (rr < N)
      feat2[(size_t)rr*CH + wv*16 + col] = fmaxf(acc[reg] + bias, 0.f);
  }
}

// ---------------- pool + MLP ----------------
__global__ __launch_bounds__(256)
void pool_mlp_kernel(const float* __restrict__ feat,
                     const int* __restrict__ batch, int N,
                     const float* __restrict__ Wp1, const float* __restrict__ bp1,
                     const float* __restrict__ Wp2, const float* __restrict__ bp2,
                     float* __restrict__ out)
{
  const int g = blockIdx.x;
  __shared__ int seg[2];
  __shared__ float part[256];
  __shared__ float pooled[CH];
  if (threadIdx.x < 2){
    int target = g + (int)threadIdx.x;
    int lo = 0, hi = N;
    while (lo < hi){ int mid = (lo + hi) >> 1; if (batch[mid] < target) lo = mid + 1; else hi = mid; }
    seg[threadIdx.x] = lo;
  }
  __syncthreads();
  const int start = seg[0], end = seg[1];
  const int c = threadIdx.x & 63, w = threadIdx.x >> 6;
  float acc = 0.f;
  for (int n = start + w; n < end; n += 4)
    acc += feat[(size_t)n*CH + c];
  part[threadIdx.x] = acc;
  __syncthreads();
  if (threadIdx.x < CH){
    float s = part[threadIdx.x] + part[threadIdx.x+64] + part[threadIdx.x+128] + part[threadIdx.x+192];
    pooled[threadIdx.x] = s / fmaxf((float)(end - start), 1.f);
  }
  __syncthreads();
  float hid = 0.f;
  if (threadIdx.x < 32){
    float a2 = bp1[threadIdx.x];
#pragma unroll
    for (int k = 0; k < CH; ++k) a2 += pooled[k] * Wp1[k*32 + threadIdx.x];
    hid = fmaxf(a2, 0.f) * Wp2[threadIdx.x];
  }
#pragma unroll
  for (int off = 16; off; off >>= 1) hid += __shfl_down(hid, off);
  if (threadIdx.x == 0) out[g] = hid + bp2[0];
}

extern "C" void kernel_launch(void* const* d_in, const int* in_sizes, int n_in,
                              void* d_out, int out_size, void* d_ws, size_t ws_size,
                              hipStream_t stream)
{
  const float* x   = (const float*)d_in[0];
  const int*   ei  = (const int*)d_in[1];
  const int*   bat = (const int*)d_in[2];
  const float* W1  = (const float*)d_in[4];
  const float* as1 = (const float*)d_in[5];
  const float* ad1 = (const float*)d_in[6];
  const float* b1  = (const float*)d_in[7];
  const float* W2  = (const float*)d_in[8];
  const float* as2 = (const float*)d_in[9];
  const float* ad2 = (const float*)d_in[10];
  const float* b2  = (const float*)d_in[11];
  const float* Wp1 = (const float*)d_in[12];
  const float* bp1 = (const float*)d_in[13];
  const float* Wp2 = (const float*)d_in[14];
  const float* bp2 = (const float*)d_in[15];

  const int N = in_sizes[0] / 8;     // x is [N, 8]
  const int E = in_sizes[1] / 2;     // edge_index is [2, E]
  const int G = out_size;            // output is [G, 1]
  const int* esrc = ei;
  const int* edst = ei + E;

  char* wsb = (char*)d_ws;
  size_t o = 0;
  auto carve = [&](size_t bytes)->char*{
    char* p = wsb + o; o += (bytes + 255) & ~(size_t)255; return p;
  };
  unsigned short* featb = (unsigned short*)carve((size_t)N*CH*sizeof(unsigned short));
  unsigned short* w2bf  = (unsigned short*)carve((size_t)HC*CH*sizeof(unsigned short));
  float* a_s      = (float*)carve((size_t)N*HEADS*sizeof(float));
  float* a_d      = (float*)carve((size_t)N*HEADS*sizeof(float));
  float* a_s2     = (float*)carve((size_t)N*HEADS*sizeof(float));
  float* a_d2     = (float*)carve((size_t)N*HEADS*sizeof(float));
  float* feat2    = (float*)carve((size_t)N*CH*sizeof(float));
  float* wfold1   = (float*)carve((size_t)64*8*sizeof(float));
  float* wfold2   = (float*)carve((size_t)64*8*sizeof(float));
  int*   rowstart = (int*)carve((size_t)N*sizeof(int));
  int*   cursor   = (int*)carve((size_t)N*sizeof(int));
  int*   deg      = (int*)carve((size_t)(N+4)*sizeof(int));   // +pad for int4 zero
  int*   bsum     = (int*)carve((size_t)512*sizeof(int));
  int*   ssrc     = (int*)carve((size_t)E*sizeof(int));

  const int nb1 = (N + 255) / 256;
  const int atb = (N + 31) / 32;
  const int gb  = (N + 15) / 16;     // group-per-dst kernels: 16 dst/block
  const int cpr = 512;               // chunks per XCD-range (grid-stride)
  const int csb = 8 * cpr;           // CSR-build grid
  const int n4  = (N + 3) / 4;       // int4 count for deg zero
  const int zb  = (n4 + 255) / 256;

  // ---- prep: folds + w2 fragments + deg zero (1 launch) ----
  prep_kernel<<<67 + zb, 256, 0, stream>>>(W1, as1, ad1, W2, as2, ad2,
                                           wfold1, wfold2, w2bf, (int4*)deg, n4);

  // ---- CSR build (real edges only; once, shared by both layers) ----
  deg_count_kernel<<<csb, 256, 0, stream>>>(edst, E, N, deg, cpr);
  scan1_kernel<<<nb1, 256, 0, stream>>>(deg, rowstart, bsum, N);
  scan2_kernel<<<1, 512, 0, stream>>>(bsum, nb1);
  scan3_kernel<<<nb1, 256, 0, stream>>>(rowstart, bsum, cursor, N);
  scatter_kernel<<<csb, 256, 0, stream>>>(esrc, edst, E, N, cursor, ssrc, cpr);

  // ---- layer 1 (Fin = 8): aggregation + projection + fused layer-2 logits ----
  att_kernel<8><<<atb, 256, 0, stream>>>(x, wfold1, a_s, a_d, N);
  gat_l1_kernel<<<gb, 256, 0, stream>>>(rowstart, ssrc, N, E, a_s, a_d, x, W1, b1,
                                        wfold2, featb, a_s2, a_d2);

  // ---- layer 2 (Fin = 64): aggregation + fused MFMA ----
  gat_z_mfma_kernel<<<gb, 256, 0, stream>>>(rowstart, ssrc, N, E, a_s2, a_d2,
                                            featb, w2bf, b2, feat2);

  // ---- pool + MLP ----
  pool_mlp_kernel<<<G, 256, 0, stream>>>(feat2, bat, N, Wp1, bp1, Wp2, bp2, (float*)d_out);
}

// Round 18
// 199.401 us; speedup vs baseline: 1.0930x; 1.0053x over previous
//
#include <hip/hip_runtime.h>

#define HEADS 4
#define CH 64
#define HC 256   // HEADS*CH
#define NEG 0.2f

typedef __attribute__((ext_vector_type(8))) short bf16x8;   // 8 bf16 (4 VGPRs)
typedef __attribute__((ext_vector_type(4))) float f32x4;    // MFMA accumulator
typedef __attribute__((ext_vector_type(2))) float f32x2;    // packed fp32 (v_pk_fma_f32)

__device__ __forceinline__ unsigned short f2bf(float f){
  unsigned u = __float_as_uint(f);
  u += 0x7fffu + ((u >> 16) & 1u);          // round-to-nearest-even
  return (unsigned short)(u >> 16);
}
__device__ __forceinline__ float bf2f(unsigned short s){
  return __uint_as_float(((unsigned)s) << 16);
}

// ---------------- fused prep: deg zero + fold8 + fold64 + w2fold (1 launch) ----------------
__global__ __launch_bounds__(256)
void prep_kernel(const float* __restrict__ W1, const float* __restrict__ as1, const float* __restrict__ ad1,
                 const float* __restrict__ W2, const float* __restrict__ as2, const float* __restrict__ ad2,
                 float* __restrict__ wfold1, float* __restrict__ wfold2,
                 unsigned short* __restrict__ w2bf,
                 int4* __restrict__ deg4, int n4)
{
  const int b = blockIdx.x;
  if (b == 0){
    int o = threadIdx.x;               // fold8: 64 outputs
    if (o < 64){
      int f = o >> 3, j = o & 7, h = j & 3;
      const float* att = (j < 4) ? as1 : ad1;
      float acc = 0.f;
#pragma unroll
      for (int c = 0; c < CH; ++c) acc += W1[(size_t)f*HC + h*CH + c] * att[h*CH + c];
      wfold1[o] = acc;
    }
  } else if (b <= 2){
    int o = (b-1)*256 + threadIdx.x;   // fold64: 512 outputs
    int f = o >> 3, j = o & 7, h = j & 3;
    const float* att = (j < 4) ? as2 : ad2;
    float acc = 0.f;
#pragma unroll
    for (int c = 0; c < CH; ++c) acc += W2[(size_t)f*HC + h*CH + c] * att[h*CH + c];
    wfold2[o] = acc;
  } else if (b < 67){
    int i = (b-3)*256 + threadIdx.x;   // w2fold: 16384 outputs
    int j  = i & 7;
    int l  = (i >> 3) & 63;
    int nf = (i >> 9) & 3;
    int kc = i >> 11;
    int q = kc*32 + (l >> 4)*8 + j;
    int c = nf*16 + (l & 15);
    int f = q & 63, h = q >> 6;
    w2bf[i] = f2bf(W2[(size_t)f*HC + h*64 + c]);
  } else {
    int i = (b-67)*256 + threadIdx.x;  // deg zero
    if (i < n4) deg4[i] = make_int4(0,0,0,0);
  }
}

// ---------------- deg_count + layer-1 att logits (independent; 1 launch) ----------------
// blocks [0,csb): XCD-range deg count.  blocks [csb, csb+atb): a_s/a_d = x @ wfold1.
__global__ __launch_bounds__(256)
void deg_att_kernel(const int* __restrict__ edst, int E, int N,
                    int* __restrict__ deg, int cpr, int csb,
                    const float* __restrict__ x, const float* __restrict__ wfold1,
                    float* __restrict__ a_s, float* __restrict__ a_d)
{
  if (blockIdx.x < csb){
    const int range = blockIdx.x & 7;
    const int lo = (int)(((long long)N * range) / 8);
    const int hi = (int)(((long long)N * (range+1)) / 8);
    const int stride = cpr * 256;
    for (int e = (blockIdx.x >> 3)*256 + threadIdx.x; e < E; e += stride){
      int d = edst[e];
      if (d >= lo && d < hi) atomicAdd(deg + d, 1);
    }
    return;
  }
  // att<8>
  __shared__ float xs[32][8];
  __shared__ float wf[64];
  const int t = threadIdx.x;
  const int n0 = (blockIdx.x - csb) * 32;
  if (t < 64) wf[t] = wfold1[t];
  for (int i = t; i < 32*8; i += 256){
    int n = n0 + (i >> 3);
    xs[i >> 3][i & 7] = (n < N) ? x[(size_t)n*8 + (i & 7)] : 0.f;
  }
  __syncthreads();
  const int nn = t >> 3, j = t & 7;
  const int n = n0 + nn;
  if (n >= N) return;
  float acc = 0.f;
#pragma unroll
  for (int f = 0; f < 8; ++f) acc += xs[nn][f] * wf[f*8 + j];
  if (j < 4) a_s[(size_t)n*4 + j]     = acc;
  else       a_d[(size_t)n*4 + (j-4)] = acc;
}

__global__ __launch_bounds__(256)
void scan1_kernel(const int* __restrict__ deg, int* __restrict__ excl,
                  int* __restrict__ bsum, int N)
{
  __shared__ int sm[256];
  int i = blockIdx.x*256 + threadIdx.x;
  int v = (i < N) ? deg[i] : 0;
  sm[threadIdx.x] = v; __syncthreads();
  for (int off = 1; off < 256; off <<= 1){
    int t = (threadIdx.x >= off) ? sm[threadIdx.x - off] : 0;
    __syncthreads();
    sm[threadIdx.x] += t;
    __syncthreads();
  }
  if (i < N) excl[i] = sm[threadIdx.x] - v;
  if (threadIdx.x == 255) bsum[blockIdx.x] = sm[255];
}

__global__ __launch_bounds__(512)
void scan2_kernel(int* __restrict__ bsum, int nb)
{
  __shared__ int sm[512];
  int v = (threadIdx.x < nb) ? bsum[threadIdx.x] : 0;
  sm[threadIdx.x] = v; __syncthreads();
  for (int off = 1; off < 512; off <<= 1){
    int t = (threadIdx.x >= off) ? sm[threadIdx.x - off] : 0;
    __syncthreads();
    sm[threadIdx.x] += t;
    __syncthreads();
  }
  if (threadIdx.x < nb) bsum[threadIdx.x] = sm[threadIdx.x] - v;
}

__global__ __launch_bounds__(256)
void scan3_kernel(int* __restrict__ excl, const int* __restrict__ bsum,
                  int* __restrict__ cursor, int N)
{
  int i = blockIdx.x*256 + threadIdx.x;
  if (i >= N) return;
  int r = excl[i] + bsum[blockIdx.x];
  excl[i] = r; cursor[i] = r;
}

__global__ __launch_bounds__(256)
void scatter_kernel(const int* __restrict__ esrc, const int* __restrict__ edst,
                    int E, int N, int* __restrict__ cursor, int* __restrict__ ssrc,
                    int cpr)
{
  const int range = blockIdx.x & 7;
  const int lo = (int)(((long long)N * range) / 8);
  const int hi = (int)(((long long)N * (range+1)) / 8);
  const int stride = cpr * 256;
  for (int e = (blockIdx.x >> 3)*256 + threadIdx.x; e < E; e += stride){
    int d = edst[e];
    if (d >= lo && d < hi){
      int pos = atomicAdd(cursor + d, 1);
      ssrc[pos] = esrc[e];
    }
  }
}

// ---------------- layer 1: group-per-dst z-aggregation + fp32 projection ----------------
// Inner loop uses packed f32x2 (v_pk_fma_f32): 4 pk ops/edge vs 8 scalar.
// Epilogue FUSES layer-2 attention logits.
__global__ __launch_bounds__(256)
void gat_l1_kernel(const int* __restrict__ rowstart, const int* __restrict__ ssrc,
                   int N, int E,
                   const float* __restrict__ a_s, const float* __restrict__ a_d,
                   const float* __restrict__ x, const float* __restrict__ W1,
                   const float* __restrict__ b1,
                   const float* __restrict__ wfold2,
                   unsigned short* __restrict__ featb,
                   float* __restrict__ a_s2, float* __restrict__ a_d2)
{
  __shared__ int    slds[4][4][16];
  __shared__ float4 wlds[4][4][16];
  __shared__ float4 zlds[16][8];     // [row][f] = (z_h0, z_h1, z_h2, z_h3)
  __shared__ float4 dnlds[16];
  __shared__ float  flds[16][65];    // fp32 feature rows (+1 pad: bank-spread)
  __shared__ float  wf2[512];        // wfold2 cache
  const int t    = threadIdx.x;
  const int wv   = t >> 6;
  const int lane = t & 63;
  const int grp  = lane >> 4;
  const int fq   = lane & 15;
  const int p    = fq >> 3;          // parity
  const int f    = fq & 7;           // feature
  const int r    = wv*4 + grp;       // local row 0..15
  const int d    = blockIdx.x*16 + r;

  wf2[t] = wfold2[t];                // 256 of 512
  wf2[256 + t] = wfold2[256 + t];

  f32x2 zp01 = {0.f, 0.f}, zp23 = {0.f, 0.f};
  f32x2 dnp01 = {0.f, 0.f}, dnp23 = {0.f, 0.f};
  if (d < N){
    const int start = rowstart[d];
    const int end   = (d == N-1) ? E : rowstart[d+1];
    const float4 ad4 = *(const float4*)(a_d + (size_t)d*4);
    // self-loop (not stored in CSR): parity 0 adds it exactly once
    {
      const float4 asd = *(const float4*)(a_s + (size_t)d*4);
      float v, es0, es1, es2, es3;
      v = asd.x + ad4.x; v = v > 0.f ? v : NEG*v; es0 = __expf(v);
      v = asd.y + ad4.y; v = v > 0.f ? v : NEG*v; es1 = __expf(v);
      v = asd.z + ad4.z; v = v > 0.f ? v : NEG*v; es2 = __expf(v);
      v = asd.w + ad4.w; v = v > 0.f ? v : NEG*v; es3 = __expf(v);
      if (p == 0){
        const float xv = x[(size_t)d*8 + f];
        const f32x2 w01 = {es0, es1}, w23 = {es2, es3};
        zp01 += w01*xv; zp23 += w23*xv;
        dnp01 += w01; dnp23 += w23;
      }
    }
    for (int base = start; base < end; base += 16){
      const int cnt = min(16, end - base);
      int sreg = 0; float e0=0.f, e1=0.f, e2=0.f, e3=0.f;
      if (fq < cnt){
        sreg = ssrc[base + fq];
        const float4 as4 = *(const float4*)(a_s + (size_t)sreg*4);
        float v;
        v = as4.x + ad4.x; v = v > 0.f ? v : NEG*v; e0 = __expf(v);
        v = as4.y + ad4.y; v = v > 0.f ? v : NEG*v; e1 = __expf(v);
        v = as4.z + ad4.z; v = v > 0.f ? v : NEG*v; e2 = __expf(v);
        v = as4.w + ad4.w; v = v > 0.f ? v : NEG*v; e3 = __expf(v);
      }
      slds[wv][grp][fq] = sreg;
      wlds[wv][grp][fq] = make_float4(e0, e1, e2, e3);
      __builtin_amdgcn_wave_barrier();
      for (int k = p; k < cnt; k += 2){
        const int    s  = slds[wv][grp][k];
        const float4 w4 = wlds[wv][grp][k];
        const float  xv = x[(size_t)s*8 + f];
        const f32x2 w01 = {w4.x, w4.y}, w23 = {w4.z, w4.w};
        zp01 += w01*xv; zp23 += w23*xv;
        dnp01 += w01; dnp23 += w23;
      }
      __builtin_amdgcn_wave_barrier();
    }
  }
  float z0 = zp01.x, z1 = zp01.y, z2 = zp23.x, z3 = zp23.y;
  float dn0 = dnp01.x, dn1 = dnp01.y, dn2 = dnp23.x, dn3 = dnp23.y;
  // combine parities (lane ^ 8 stays within the 16-lane group)
  z0  += __shfl_xor(z0, 8);  z1  += __shfl_xor(z1, 8);
  z2  += __shfl_xor(z2, 8);  z3  += __shfl_xor(z3, 8);
  dn0 += __shfl_xor(dn0, 8); dn1 += __shfl_xor(dn1, 8);
  dn2 += __shfl_xor(dn2, 8); dn3 += __shfl_xor(dn3, 8);
  if (d >= N){ dn0=dn1=dn2=dn3=1.f; }
  if (fq < 8)  zlds[r][f] = make_float4(z0, z1, z2, z3);
  if (fq == 0) dnlds[r]   = make_float4(dn0, dn1, dn2, dn3);
  __syncthreads();
  // fp32 finish: wave wv handles rows wv*4..wv*4+3; lane = output channel
  float Wf[4][8];
#pragma unroll
  for (int h = 0; h < 4; ++h)
#pragma unroll
    for (int ff = 0; ff < 8; ++ff)
      Wf[h][ff] = W1[ff*HC + h*CH + lane];
  const float bc = b1[lane];
#pragma unroll
  for (int i = 0; i < 4; ++i){
    const int r2 = wv*4 + i;
    const int d2 = blockIdx.x*16 + r2;
    if (d2 >= N) break;
    const float4 dn = dnlds[r2];
    float a0=0.f, a1=0.f, a2=0.f, a3=0.f;
#pragma unroll
    for (int ff = 0; ff < 8; ++ff){
      const float4 q = zlds[r2][ff];
      a0 += q.x*Wf[0][ff]; a1 += q.y*Wf[1][ff];
      a2 += q.z*Wf[2][ff]; a3 += q.w*Wf[3][ff];
    }
    float val = 0.25f*(a0*__builtin_amdgcn_rcpf(dn.x) + a1*__builtin_amdgcn_rcpf(dn.y)
                     + a2*__builtin_amdgcn_rcpf(dn.z) + a3*__builtin_amdgcn_rcpf(dn.w));
    val = fmaxf(val + bc, 0.f);
    featb[(size_t)d2*CH + lane] = f2bf(val);
    flds[r2][lane] = val;
  }
  __syncthreads();
  // fused layer-2 logits: a_s2/a_d2 = row @ wfold2 (separate buffers: no race)
  if (t < 128){
    const int nn = t >> 3, j = t & 7;
    const int n = blockIdx.x*16 + nn;
    if (n < N){
      float acc = 0.f;
#pragma unroll
      for (int ch = 0; ch < 64; ++ch) acc += flds[nn][ch] * wf2[ch*8 + j];
      if (j < 4) a_s2[(size_t)n*4 + j]     = acc;
      else       a_d2[(size_t)n*4 + (j-4)] = acc;
    }
  }
}

// ---------------- layer 2: group-per-dst aggregation + fused MFMA finish ----------------
// Inner loop packed f32x2: 8 pk_fma + 2 pk_add per edge vs 20 scalar.
__global__ __launch_bounds__(256)
void gat_z_mfma_kernel(const int* __restrict__ rowstart, const int* __restrict__ ssrc,
                       int N, int E,
                       const float* __restrict__ a_s, const float* __restrict__ a_d,
                       const unsigned short* __restrict__ featb,
                       const unsigned short* __restrict__ w2bf,
                       const float* __restrict__ b2,
                       float* __restrict__ feat2)
{
  __shared__ int    slds[4][4][16];
  __shared__ float4 wlds[4][4][16];
  __shared__ unsigned short zlds[16][264];   // row stride 528B -> 2-way banks
  const int t    = threadIdx.x;
  const int wv   = t >> 6;
  const int lane = t & 63;
  const int grp  = lane >> 4;
  const int fq   = lane & 15;
  const int r    = wv*4 + grp;               // local row 0..15
  const int d    = blockIdx.x*16 + r;

  // zp[h][j]: features (2j, 2j+1) for head h
  f32x2 zp[4][2] = {{{0,0},{0,0}},{{0,0},{0,0}},{{0,0},{0,0}},{{0,0},{0,0}}};
  f32x2 dnp01 = {1.f, 1.f}, dnp23 = {1.f, 1.f};   // safe default for d>=N
  if (d < N){
    const int start = rowstart[d];
    const int end   = (d == N-1) ? E : rowstart[d+1];
    const float4 ad4 = *(const float4*)(a_d + (size_t)d*4);
    const ushort4* __restrict__ fb4 = (const ushort4*)featb;
    // self-loop (den replicated per lane; z at own feature-quad)
    {
      const float4 asd = *(const float4*)(a_s + (size_t)d*4);
      float v, es0, es1, es2, es3;
      v = asd.x + ad4.x; v = v > 0.f ? v : NEG*v; es0 = __expf(v);
      v = asd.y + ad4.y; v = v > 0.f ? v : NEG*v; es1 = __expf(v);
      v = asd.z + ad4.z; v = v > 0.f ? v : NEG*v; es2 = __expf(v);
      v = asd.w + ad4.w; v = v > 0.f ? v : NEG*v; es3 = __expf(v);
      const ushort4 hv = fb4[(size_t)d*16 + fq];
      const f32x2 f01 = {bf2f(hv.x), bf2f(hv.y)};
      const f32x2 f23 = {bf2f(hv.z), bf2f(hv.w)};
      zp[0][0] = es0*f01; zp[0][1] = es0*f23;
      zp[1][0] = es1*f01; zp[1][1] = es1*f23;
      zp[2][0] = es2*f01; zp[2][1] = es2*f23;
      zp[3][0] = es3*f01; zp[3][1] = es3*f23;
      dnp01 = f32x2{es0, es1}; dnp23 = f32x2{es2, es3};
    }
    for (int base = start; base < end; base += 16){
      const int cnt = min(16, end - base);
      int sreg = 0; float e0=0.f, e1=0.f, e2=0.f, e3=0.f;
      if (fq < cnt){
        sreg = ssrc[base + fq];
        const float4 as4 = *(const float4*)(a_s + (size_t)sreg*4);
        float v;
        v = as4.x + ad4.x; v = v > 0.f ? v : NEG*v; e0 = __expf(v);
        v = as4.y + ad4.y; v = v > 0.f ? v : NEG*v; e1 = __expf(v);
        v = as4.z + ad4.z; v = v > 0.f ? v : NEG*v; e2 = __expf(v);
        v = as4.w + ad4.w; v = v > 0.f ? v : NEG*v; e3 = __expf(v);
      }
      slds[wv][grp][fq] = sreg;
      wlds[wv][grp][fq] = make_float4(e0, e1, e2, e3);
      __builtin_amdgcn_wave_barrier();
#define ACC_EDGE(W4, HV) do{ \
        const f32x2 f01_ = {bf2f((HV).x), bf2f((HV).y)}; \
        const f32x2 f23_ = {bf2f((HV).z), bf2f((HV).w)}; \
        zp[0][0] += (W4).x*f01_; zp[0][1] += (W4).x*f23_; \
        zp[1][0] += (W4).y*f01_; zp[1][1] += (W4).y*f23_; \
        zp[2][0] += (W4).z*f01_; zp[2][1] += (W4).z*f23_; \
        zp[3][0] += (W4).w*f01_; zp[3][1] += (W4).w*f23_; \
        dnp01 += f32x2{(W4).x, (W4).y}; dnp23 += f32x2{(W4).z, (W4).w}; }while(0)
      int k = 0;
      for (; k + 3 < cnt; k += 4){
        const int sA = slds[wv][grp][k],   sB = slds[wv][grp][k+1];
        const int sC = slds[wv][grp][k+2], sD = slds[wv][grp][k+3];
        const ushort4 hA = fb4[(size_t)sA*16 + fq];
        const ushort4 hB = fb4[(size_t)sB*16 + fq];
        const ushort4 hC = fb4[(size_t)sC*16 + fq];
        const ushort4 hD = fb4[(size_t)sD*16 + fq];
        const float4 wA = wlds[wv][grp][k],   wB = wlds[wv][grp][k+1];
        const float4 wC = wlds[wv][grp][k+2], wD = wlds[wv][grp][k+3];
        ACC_EDGE(wA, hA); ACC_EDGE(wB, hB); ACC_EDGE(wC, hC); ACC_EDGE(wD, hD);
      }
      for (; k < cnt; ++k){
        const int    s  = slds[wv][grp][k];
        const float4 w4 = wlds[wv][grp][k];
        const ushort4 hv = fb4[(size_t)s*16 + fq];
        ACC_EDGE(w4, hv);
      }
#undef ACC_EDGE
      __builtin_amdgcn_wave_barrier();
    }
  }
  {
    const float s0 = 0.25f*__builtin_amdgcn_rcpf(dnp01.x);
    const float s1 = 0.25f*__builtin_amdgcn_rcpf(dnp01.y);
    const float s2 = 0.25f*__builtin_amdgcn_rcpf(dnp23.x);
    const float s3 = 0.25f*__builtin_amdgcn_rcpf(dnp23.y);
    ushort4* zrow = (ushort4*)zlds[r];
    ushort4 o;
    o.x=f2bf(zp[0][0].x*s0); o.y=f2bf(zp[0][0].y*s0); o.z=f2bf(zp[0][1].x*s0); o.w=f2bf(zp[0][1].y*s0);
    zrow[ 0 + fq] = o;
    o.x=f2bf(zp[1][0].x*s1); o.y=f2bf(zp[1][0].y*s1); o.z=f2bf(zp[1][1].x*s1); o.w=f2bf(zp[1][1].y*s1);
    zrow[16 + fq] = o;
    o.x=f2bf(zp[2][0].x*s2); o.y=f2bf(zp[2][0].y*s2); o.z=f2bf(zp[2][1].x*s2); o.w=f2bf(zp[2][1].y*s2);
    zrow[32 + fq] = o;
    o.x=f2bf(zp[3][0].x*s3); o.y=f2bf(zp[3][0].y*s3); o.z=f2bf(zp[3][1].x*s3); o.w=f2bf(zp[3][1].y*s3);
    zrow[48 + fq] = o;
  }
  __syncthreads();
  const bf16x8* __restrict__ bfr = (const bf16x8*)w2bf;
  const int arow = lane & 15;
  const int kg   = lane >> 4;
  f32x4 acc = {0.f, 0.f, 0.f, 0.f};
#pragma unroll
  for (int kc = 0; kc < 8; ++kc){
    const bf16x8 a = *(const bf16x8*)(&zlds[arow][kc*32 + kg*8]);
    const bf16x8 b = bfr[(kc*4 + wv)*64 + lane];
    acc = __builtin_amdgcn_mfma_f32_16x16x32_bf16(a, b, acc, 0, 0, 0);
  }
  const int col = lane & 15;                 // C: col=lane&15, row=(lane>>4)*4+reg
  const float bias = b2[wv*16 + col];
#pragma unroll
  for (int reg = 0; reg < 4; ++reg){
    const int rr = blockIdx.x*16 + kg*4 + reg;
    if (rr < N)
      feat2[(size_t)rr*CH + wv*16 + col] = fmaxf(acc[reg] + bias, 0.f);
  }
}

// ---------------- pool + MLP ----------------
__global__ __launch_bounds__(256)
void pool_mlp_kernel(const float* __restrict__ feat,
                     const int* __restrict__ batch, int N,
                     const float* __restrict__ Wp1, const float* __restrict__ bp1,
                     const float* __restrict__ Wp2, const float* __restrict__ bp2,
                     float* __restrict__ out)
{
  const int g = blockIdx.x;
  __shared__ int seg[2];
  __shared__ float part[256];
  __shared__ float pooled[CH];
  if (threadIdx.x < 2){
    int target = g + (int)threadIdx.x;
    int lo = 0, hi = N;
    while (lo < hi){ int mid = (lo + hi) >> 1; if (batch[mid] < target) lo = mid + 1; else hi = mid; }
    seg[threadIdx.x] = lo;
  }
  __syncthreads();
  const int start = seg[0], end = seg[1];
  const int c = threadIdx.x & 63, w = threadIdx.x >> 6;
  float acc = 0.f;
  for (int n = start + w; n < end; n += 4)
    acc += feat[(size_t)n*CH + c];
  part[threadIdx.x] = acc;
  __syncthreads();
  if (threadIdx.x < CH){
    float s = part[threadIdx.x] + part[threadIdx.x+64] + part[threadIdx.x+128] + part[threadIdx.x+192];
    pooled[threadIdx.x] = s / fmaxf((float)(end - start), 1.f);
  }
  __syncthreads();
  float hid = 0.f;
  if (threadIdx.x < 32){
    float a2 = bp1[threadIdx.x];
#pragma unroll
    for (int k = 0; k < CH; ++k) a2 += pooled[k] * Wp1[k*32 + threadIdx.x];
    hid = fmaxf(a2, 0.f) * Wp2[threadIdx.x];
  }
#pragma unroll
  for (int off = 16; off; off >>= 1) hid += __shfl_down(hid, off);
  if (threadIdx.x == 0) out[g] = hid + bp2[0];
}

extern "C" void kernel_launch(void* const* d_in, const int* in_sizes, int n_in,
                              void* d_out, int out_size, void* d_ws, size_t ws_size,
                              hipStream_t stream)
{
  const float* x   = (const float*)d_in[0];
  const int*   ei  = (const int*)d_in[1];
  const int*   bat = (const int*)d_in[2];
  const float* W1  = (const float*)d_in[4];
  const float* as1 = (const float*)d_in[5];
  const float* ad1 = (const float*)d_in[6];
  const float* b1  = (const float*)d_in[7];
  const float* W2  = (const float*)d_in[8];
  const float* as2 = (const float*)d_in[9];
  const float* ad2 = (const float*)d_in[10];
  const float* b2  = (const float*)d_in[11];
  const float* Wp1 = (const float*)d_in[12];
  const float* bp1 = (const float*)d_in[13];
  const float* Wp2 = (const float*)d_in[14];
  const float* bp2 = (const float*)d_in[15];

  const int N = in_sizes[0] / 8;     // x is [N, 8]
  const int E = in_sizes[1] / 2;     // edge_index is [2, E]
  const int G = out_size;            // output is [G, 1]
  const int* esrc = ei;
  const int* edst = ei + E;

  char* wsb = (char*)d_ws;
  size_t o = 0;
  auto carve = [&](size_t bytes)->char*{
    char* p = wsb + o; o += (bytes + 255) & ~(size_t)255; return p;
  };
  unsigned short* featb = (unsigned short*)carve((size_t)N*CH*sizeof(unsigned short));
  unsigned short* w2bf  = (unsigned short*)carve((size_t)HC*CH*sizeof(unsigned short));
  float* a_s      = (float*)carve((size_t)N*HEADS*sizeof(float));
  float* a_d      = (float*)carve((size_t)N*HEADS*sizeof(float));
  float* a_s2     = (float*)carve((size_t)N*HEADS*sizeof(float));
  float* a_d2     = (float*)carve((size_t)N*HEADS*sizeof(float));
  float* feat2    = (float*)carve((size_t)N*CH*sizeof(float));
  float* wfold1   = (float*)carve((size_t)64*8*sizeof(float));
  float* wfold2   = (float*)carve((size_t)64*8*sizeof(float));
  int*   rowstart = (int*)carve((size_t)N*sizeof(int));
  int*   cursor   = (int*)carve((size_t)N*sizeof(int));
  int*   deg      = (int*)carve((size_t)(N+4)*sizeof(int));   // +pad for int4 zero
  int*   bsum     = (int*)carve((size_t)512*sizeof(int));
  int*   ssrc     = (int*)carve((size_t)E*sizeof(int));

  const int nb1 = (N + 255) / 256;
  const int atb = (N + 31) / 32;
  const int gb  = (N + 15) / 16;     // group-per-dst kernels: 16 dst/block
  const int cpr = 512;               // chunks per XCD-range (grid-stride)
  const int csb = 8 * cpr;           // CSR-build grid
  const int n4  = (N + 3) / 4;       // int4 count for deg zero
  const int zb  = (n4 + 255) / 256;

  // ---- prep: folds + w2 fragments + deg zero (1 launch) ----
  prep_kernel<<<67 + zb, 256, 0, stream>>>(W1, as1, ad1, W2, as2, ad2,
                                           wfold1, wfold2, w2bf, (int4*)deg, n4);

  // ---- deg count + layer-1 att logits (independent; 1 launch) ----
  deg_att_kernel<<<csb + atb, 256, 0, stream>>>(edst, E, N, deg, cpr, csb,
                                                x, wfold1, a_s, a_d);
  scan1_kernel<<<nb1, 256, 0, stream>>>(deg, rowstart, bsum, N);
  scan2_kernel<<<1, 512, 0, stream>>>(bsum, nb1);
  scan3_kernel<<<nb1, 256, 0, stream>>>(rowstart, bsum, cursor, N);
  scatter_kernel<<<csb, 256, 0, stream>>>(esrc, edst, E, N, cursor, ssrc, cpr);

  // ---- layer 1 (Fin = 8): aggregation + projection + fused layer-2 logits ----
  gat_l1_kernel<<<gb, 256, 0, stream>>>(rowstart, ssrc, N, E, a_s, a_d, x, W1, b1,
                                        wfold2, featb, a_s2, a_d2);

  // ---- layer 2 (Fin = 64): aggregation + fused MFMA ----
  gat_z_mfma_kernel<<<gb, 256, 0, stream>>>(rowstart, ssrc, N, E, a_s2, a_d2,
                                            featb, w2bf, b2, feat2);

  // ---- pool + MLP ----
  pool_mlp_kernel<<<G, 256, 0, stream>>>(feat2, bat, N, Wp1, bp1, Wp2, bp2, (float*)d_out);
}